// Round 1
// baseline (104286.682 us; speedup 1.0000x reference)
//
#include <hip/hip_runtime.h>
#include <stdint.h>

#define NWG   250      // workgroups (<= 256 CUs -> all co-resident)
#define RPW   8        // reservoir rows per WG  (250*8 = 2000)
#define RDIM  2000
#define KPAD  2048     // padded k-extent (zeros beyond 2000)
#define NSTEP 14336    // B*T sequential steps
#define TT    28       // time steps per batch element
#define NB    512
#define NO    10
#define BLK   256

// Persistent ESN kernel. One WG per CU; W_res slice in registers; h broadcast
// through L3 via agent-scope atomics; all-to-all flag barrier per step.
__global__ __launch_bounds__(BLK, 1)
void esn_persistent(const float* __restrict__ x,
                    const float* __restrict__ Win,
                    const float* __restrict__ Wres,
                    const float* __restrict__ Wout,
                    float* __restrict__ out,
                    float* __restrict__ ws)
{
    const int tid = threadIdx.x;
    const int wg  = blockIdx.x;
    const int g   = tid >> 5;      // row-in-slice 0..7 (32 lanes per row)
    const int l32 = tid & 31;
    const int row = wg * RPW + g;

    float* hb0 = ws;               // h buffer, parity 0  [KPAD]
    float* hb1 = ws + KPAD;        // h buffer, parity 1  [KPAD]
    int*  flags = (int*)(ws + 2 * KPAD);   // [NWG], memset to 0 each launch

    __shared__ __align__(16) float h_lds[KPAD];
    __shared__ float x_lds[32];
    __shared__ float win_lds[RPW * 32];
    __shared__ float hl_lds[RPW];
    __shared__ float out_lds[NB * NO];     // per-WG partial outputs (20 KB)

    // ---- init ----
    for (int i = tid; i < KPAD; i += BLK) h_lds[i] = 0.f;   // h_0 = 0 (+ pad)
    {
        const int gg = tid >> 5, ll = tid & 31;
        win_lds[tid] = (ll < TT) ? Win[(wg * RPW + gg) * TT + ll] : 0.f;
    }
    for (int i = tid; i < NB * NO; i += BLK) out_lds[i] = 0.f;

    // W_res slice -> registers: thread (g,l32) holds k = c*128 + l32*4 .. +3
    float4 wr[16];
    {
        const float* wrow = Wres + (size_t)row * RDIM;
        #pragma unroll
        for (int c = 0; c < 16; ++c) {
            const int k = c * 128 + l32 * 4;
            if (k < RDIM) wr[c] = *(const float4*)(wrow + k);
            else          wr[c] = make_float4(0.f, 0.f, 0.f, 0.f);
        }
    }
    __syncthreads();

    int bcur = 0, tt = 0;
    for (int t = 0; t < NSTEP; ++t) {
        // prefetch x_t (read-only input: normal cached load, never stale)
        float xv = 0.f;
        if (tid < TT) xv = x[t * TT + tid];

        const float* hrd = (t & 1) ? hb1 : hb0;
        float*       hwr = (t & 1) ? hb0 : hb1;

        if (t > 0 && tid < NWG) {
            // wait only for the producer of the slice THIS thread consumes
            while (__hip_atomic_load(&flags[tid], __ATOMIC_RELAXED,
                                     __HIP_MEMORY_SCOPE_AGENT) < t) { }
            uint64_t* src = (uint64_t*)(hrd + tid * 8);
            uint64_t a0 = __hip_atomic_load(src + 0, __ATOMIC_RELAXED, __HIP_MEMORY_SCOPE_AGENT);
            uint64_t a1 = __hip_atomic_load(src + 1, __ATOMIC_RELAXED, __HIP_MEMORY_SCOPE_AGENT);
            uint64_t a2 = __hip_atomic_load(src + 2, __ATOMIC_RELAXED, __HIP_MEMORY_SCOPE_AGENT);
            uint64_t a3 = __hip_atomic_load(src + 3, __ATOMIC_RELAXED, __HIP_MEMORY_SCOPE_AGENT);
            uint64_t* dst = (uint64_t*)(h_lds + tid * 8);
            dst[0] = a0; dst[1] = a1; dst[2] = a2; dst[3] = a3;
        }
        if (tid < TT) x_lds[tid] = xv;
        __syncthreads();

        // matvec: acc(g,l32) = sum_k W[row][k]*h[k] over this lane's k-slice
        float acc = 0.f;
        #pragma unroll
        for (int c = 0; c < 16; ++c) {
            const float4 hv = *(const float4*)(h_lds + c * 128 + l32 * 4);
            acc = fmaf(wr[c].x, hv.x, acc);
            acc = fmaf(wr[c].y, hv.y, acc);
            acc = fmaf(wr[c].z, hv.z, acc);
            acc = fmaf(wr[c].w, hv.w, acc);
        }
        // fold in u_t[row] = x_t . W_in[row]
        if (l32 < TT) acc = fmaf(x_lds[l32], win_lds[g * 32 + l32], acc);
        #pragma unroll
        for (int off = 16; off > 0; off >>= 1)
            acc += __shfl_down(acc, off, 32);

        const bool last = (tt == TT - 1);
        if (l32 == 0) {
            const float hn = tanhf(acc);
            __hip_atomic_store(&hwr[row], hn, __ATOMIC_RELAXED,
                               __HIP_MEMORY_SCOPE_AGENT);   // write-through to L3
            if (last) hl_lds[g] = hn;
        }
        __syncthreads();   // compiler drains vmcnt(0) here -> h stores visible

        if (last && tid < NO) {
            float s = 0.f;
            #pragma unroll
            for (int g2 = 0; g2 < RPW; ++g2)
                s += hl_lds[g2] * Wout[tid * RDIM + wg * RPW + g2];
            out_lds[bcur * NO + tid] += s;
        }
        if (tid == 0)
            __hip_atomic_store(&flags[wg], t + 1, __ATOMIC_RELEASE,
                               __HIP_MEMORY_SCOPE_AGENT);
        if (++tt == TT) { tt = 0; ++bcur; }
    }

    __syncthreads();
    // out was memset to 0 on the stream before this kernel
    for (int i = tid; i < NB * NO; i += BLK)
        atomicAdd(&out[i], out_lds[i]);
}

extern "C" void kernel_launch(void* const* d_in, const int* in_sizes, int n_in,
                              void* d_out, int out_size, void* d_ws, size_t ws_size,
                              hipStream_t stream)
{
    const float* x    = (const float*)d_in[0];
    const float* Win  = (const float*)d_in[1];
    const float* Wres = (const float*)d_in[2];
    const float* Wout = (const float*)d_in[3];
    float* out = (float*)d_out;
    float* ws  = (float*)d_ws;

    // flags must start < 1 (0xAA poison is a LARGE value as unsigned; as int
    // it's negative, but memset-to-0 makes the protocol robust either way)
    hipMemsetAsync(ws + 2 * KPAD, 0, NWG * sizeof(int), stream);
    hipMemsetAsync(d_out, 0, (size_t)out_size * sizeof(float), stream);

    hipLaunchKernelGGL(esn_persistent, dim3(NWG), dim3(BLK), 0, stream,
                       x, Win, Wres, Wout, out, ws);
}

// Round 3
// 16695.236 us; speedup vs baseline: 6.2465x; 6.2465x over previous
//
#include <hip/hip_runtime.h>
#include <stdint.h>

#define NWG   250      // one WG per CU; 250*8 = 2000 reservoir rows
#define RPW   8        // rows per WG (fp32 W_res slice in VGPRs: 64 KB/CU)
#define RDIM  2000
#define KPAD  2048
#define NC    16       // parallel chunks (columns of the batched matvec)
#define CHL   896      // 14336 / NC steps owned per chunk
#define WARM  112      // warmup steps (echo-state contraction ~0.75^112)
#define SSTEPS (WARM + CHL)   // 1008 sequential steps
#define TT    28
#define NB    512
#define NO    10
#define BLK   256

// Chunked column-batched ESN: H[2000][16] stepped 1008 times by 250 CUs.
// W_res rows in registers; H broadcast through the coherence point with
// RELAXED agent atomics; per-producer flag after __syncthreads vmcnt drain.
__global__ __launch_bounds__(BLK, 1)
void esn_chunked(const float* __restrict__ x,
                 const float* __restrict__ Win,
                 const float* __restrict__ Wres,
                 const float* __restrict__ Wout,
                 float* __restrict__ out,
                 float* __restrict__ ws)
{
    const int tid = threadIdx.x;
    const int wg  = blockIdx.x;
    const int g   = tid >> 5;      // row-in-slice 0..7
    const int l32 = tid & 31;      // 32 lanes per row: k-sliced
    const int row = wg * RPW + g;

    float* bufA = ws;                       // H state, parity 0 [NC][KPAD]
    float* bufB = ws + NC * KPAD;           // H state, parity 1
    int*  flags = (int*)(ws + 2 * NC * KPAD);  // [NWG], memset 0 per launch

    extern __shared__ float Hdyn[];         // [NC][KPAD] fp32 = 128 KB dynamic
    float (*H)[KPAD] = (float (*)[KPAD])Hdyn;

    __shared__ float win_lds[RPW * 32];
    __shared__ float x_lds[NC][32];
    __shared__ float hnew[NC][RPW];
    __shared__ float wout_lds[NO * RPW];

    // ---- init ----
    for (int i = tid; i < NC * KPAD; i += BLK) Hdyn[i] = 0.f;  // incl. k-pad
    win_lds[tid] = (l32 < TT) ? Win[(wg * RPW + g) * TT + l32] : 0.f;
    if (tid < NO * RPW)
        wout_lds[tid] = Wout[(tid / RPW) * RDIM + wg * RPW + (tid % RPW)];

    // W_res slice -> registers: lane l32 owns k = cc*128 + l32*4 .. +3
    float4 wr[16];
    {
        const float* wrow = Wres + (size_t)row * RDIM;
        #pragma unroll
        for (int cc = 0; cc < 16; ++cc) {
            const int k = cc * 128 + l32 * 4;
            if (k < RDIM) wr[cc] = *(const float4*)(wrow + k);
            else          wr[cc] = make_float4(0.f, 0.f, 0.f, 0.f);
        }
    }
    __syncthreads();

    for (int j = 0; j < SSTEPS; ++j) {
        const float* rb   = (j & 1) ? bufB : bufA;
        float*       wbuf = (j & 1) ? bufA : bufB;

        // x rows for this step: col c is at global step g_c = c*CHL - WARM + j
        #pragma unroll
        for (int half = 0; half < 2; ++half) {
            const int c  = g + half * 8;
            const int gg = c * CHL - WARM + j;
            if (l32 < TT) x_lds[c][l32] = (gg >= 0) ? x[gg * TT + l32] : 0.f;
        }

        // wait for producer tid, gather its 8 rows x 16 cols (512 B) into LDS
        if (tid < NWG) {
            while (__hip_atomic_load(&flags[tid], __ATOMIC_RELAXED,
                                     __HIP_MEMORY_SCOPE_AGENT) < j) { }
            const int kb = tid * RPW;
            #pragma unroll
            for (int c = 0; c < NC; ++c) {
                const uint64_t* src = (const uint64_t*)(rb + c * KPAD + kb);
                uint64_t a0 = __hip_atomic_load(src + 0, __ATOMIC_RELAXED, __HIP_MEMORY_SCOPE_AGENT);
                uint64_t a1 = __hip_atomic_load(src + 1, __ATOMIC_RELAXED, __HIP_MEMORY_SCOPE_AGENT);
                uint64_t a2 = __hip_atomic_load(src + 2, __ATOMIC_RELAXED, __HIP_MEMORY_SCOPE_AGENT);
                uint64_t a3 = __hip_atomic_load(src + 3, __ATOMIC_RELAXED, __HIP_MEMORY_SCOPE_AGENT);
                uint64_t* dst = (uint64_t*)&H[c][kb];
                dst[0] = a0; dst[1] = a1; dst[2] = a2; dst[3] = a3;
            }
        }
        __syncthreads();

        // 8 rows x 16 cols per WG: lane-parallel over k, 4 acc chains for ILP
        float pre[NC];
        #pragma unroll
        for (int c = 0; c < NC; ++c) {
            float a0 = 0.f, a1 = 0.f, a2 = 0.f, a3 = 0.f;
            const float4* hp = (const float4*)&H[c][0];
            #pragma unroll
            for (int cc = 0; cc < 16; ++cc) {
                const float4 hv = hp[cc * 32 + l32];
                a0 = fmaf(wr[cc].x, hv.x, a0);
                a1 = fmaf(wr[cc].y, hv.y, a1);
                a2 = fmaf(wr[cc].z, hv.z, a2);
                a3 = fmaf(wr[cc].w, hv.w, a3);
            }
            float acc = (a0 + a1) + (a2 + a3);
            if (l32 < TT) acc = fmaf(x_lds[c][l32], win_lds[g * 32 + l32], acc);
            #pragma unroll
            for (int off = 16; off > 0; off >>= 1)
                acc += __shfl_down(acc, off, 32);
            pre[c] = acc;     // valid on lane 0
        }

        if (l32 == 0) {
            #pragma unroll
            for (int c = 0; c < NC; ++c) {
                const float hv = tanhf(pre[c]);
                hnew[c][g] = hv;
                __hip_atomic_store(wbuf + c * KPAD + row, hv,
                                   __ATOMIC_RELAXED, __HIP_MEMORY_SCOPE_AGENT);
            }
        }
        __syncthreads();   // drains vmcnt(0): h stores acked at coherence point
        if (tid == 0)
            __hip_atomic_store(&flags[wg], j + 1, __ATOMIC_RELAXED,
                               __HIP_MEMORY_SCOPE_AGENT);

        // output rows: every col hits its h_last at j = 27 (mod 28), j >= 139
        if (j >= WARM + TT - 1 && ((j - (TT - 1)) % TT) == 0 && tid < NC * NO) {
            const int c = tid / NO, o = tid % NO;
            const int m = (CHL / TT) * c + (j - (WARM + TT - 1)) / TT;
            float s = 0.f;
            #pragma unroll
            for (int r2 = 0; r2 < RPW; ++r2)
                s += hnew[c][r2] * wout_lds[o * RPW + r2];
            atomicAdd(&out[m * NO + o], s);   // fire-and-forget, off crit path
        }
    }
}

extern "C" void kernel_launch(void* const* d_in, const int* in_sizes, int n_in,
                              void* d_out, int out_size, void* d_ws, size_t ws_size,
                              hipStream_t stream)
{
    const float* x    = (const float*)d_in[0];
    const float* Win  = (const float*)d_in[1];
    const float* Wres = (const float*)d_in[2];
    const float* Wout = (const float*)d_in[3];
    float* out = (float*)d_out;
    float* ws  = (float*)d_ws;

    // zero both H buffers + flags (poison 0xAA must never satisfy protocol)
    hipMemsetAsync(ws, 0, (2 * NC * KPAD) * sizeof(float) + NWG * sizeof(int), stream);
    hipMemsetAsync(d_out, 0, (size_t)out_size * sizeof(float), stream);

    // 128 KB dynamic LDS (gfx950 HW max 160 KB); attribute call is a no-op
    // safeguard on stacks that gate >64 KB
    (void)hipFuncSetAttribute((const void*)esn_chunked,
                              hipFuncAttributeMaxDynamicSharedMemorySize,
                              NC * KPAD * (int)sizeof(float));

    hipLaunchKernelGGL(esn_chunked, dim3(NWG), dim3(BLK),
                       NC * KPAD * sizeof(float), stream,
                       x, Win, Wres, Wout, out, ws);
}

// Round 7
// 10586.106 us; speedup vs baseline: 9.8513x; 1.5771x over previous
//
#include <hip/hip_runtime.h>
#include <stdint.h>

#define NWG   125      // 125 WGs x 512 thr; 16 rows/WG -> 2000 rows exact
#define BLK   512
#define RPW   16
#define RDIM  2000
#define KPAD  2048
#define NC    16       // parallel chunks (columns)
#define CHL   896      // 14336 / NC
#define WARM  112      // echo-state warmup
#define SSTEPS (WARM + CHL)   // 1008 sequential steps
#define TT    28
#define NO    10

static __device__ __forceinline__ unsigned short f32_to_bf16(float f) {
    union { float f; unsigned u; } v; v.f = f;
    unsigned r = v.u + 0x7FFFu + ((v.u >> 16) & 1u);   // RNE
    return (unsigned short)(r >> 16);
}

// Chunked column-batched ESN, bf16 state transport.
// Wave layout: wave = (row-quad rq, k-half kh); 16-lane k-groups give
// conflict-free 256B-contiguous ds_read_b128 with 4-way lane broadcast.
__global__ __launch_bounds__(BLK)
void esn_chunked2(const float* __restrict__ x,
                  const float* __restrict__ Win,
                  const float* __restrict__ Wres,
                  const float* __restrict__ Wout,
                  float* __restrict__ out,
                  unsigned short* __restrict__ ws16)
{
    const int tid  = threadIdx.x;
    const int wg   = blockIdx.x;
    const int wv   = tid >> 6;         // wave 0..7
    const int lane = tid & 63;
    const int rq   = wv & 3;           // row-quad 0..3
    const int kh   = wv >> 2;          // k-half 0..1
    const int g16  = lane >> 4;        // 0..3
    const int l16  = lane & 15;
    const int rloc = rq * 4 + g16;     // local row 0..15
    const int row  = wg * RPW + rloc;
    const int kbase = kh * 1024;

    unsigned short* bufA = ws16;                  // h parity 0 [NC][KPAD] bf16
    unsigned short* bufB = ws16 + NC * KPAD;      // h parity 1
    int* flags = (int*)(ws16 + 2 * NC * KPAD);    // [NWG], memset 0

    extern __shared__ float Hdyn[];               // [NC][KPAD] fp32 = 128 KB
    float (*H)[KPAD] = (float (*)[KPAD])Hdyn;
    __shared__ float x_lds[NC][32];
    __shared__ float win_lds[RPW][32];
    __shared__ float partial[2][NC][RPW];
    __shared__ float hnew[NC][RPW];
    __shared__ float wout_lds[NO][RPW];

    // ---- init ----
    for (int i = tid; i < NC * KPAD; i += BLK) Hdyn[i] = 0.f;  // h0=0 + pads
    { int r = tid >> 5, l = tid & 31;
      win_lds[r][l] = (l < TT) ? Win[(wg * RPW + r) * TT + l] : 0.f; }
    if (tid < NO * RPW) {
        int o = tid / RPW, r = tid % RPW;
        wout_lds[o][r] = Wout[o * RDIM + wg * RPW + r];
    }
    // W_res: lane (rq,kh,g16,l16) holds row, k = kbase + cc*64 + l16*4
    float4 wr[16];
    {
        const float* wrow = Wres + (size_t)row * RDIM;
        #pragma unroll
        for (int cc = 0; cc < 16; ++cc) {
            int k = kbase + cc * 64 + l16 * 4;
            wr[cc] = (k < RDIM) ? *(const float4*)(wrow + k)
                                : make_float4(0.f, 0.f, 0.f, 0.f);
        }
    }
    __syncthreads();

    for (int j = 0; j < SSTEPS; ++j) {
        // x_t for all 16 cols (prefetch before poll; independent)
        { int c = tid >> 5, l = tid & 31;
          if (l < TT) {
              int gg = c * CHL - WARM + j;
              x_lds[c][l] = (gg >= 0) ? x[gg * TT + l] : 0.f;
          } }

        // gather: thread (p,q) pulls producer p's quarter-slice, all 16 cols
        if (j > 0 && tid < 500) {
            const unsigned short* rb = (j & 1) ? bufB : bufA;
            const int p = tid >> 2, q = tid & 3;
            while (__hip_atomic_load(&flags[p], __ATOMIC_RELAXED,
                                     __HIP_MEMORY_SCOPE_AGENT) < j) { }
            unsigned long long vv[NC];
            #pragma unroll
            for (int c = 0; c < NC; ++c) {
                const unsigned long long* src =
                    (const unsigned long long*)(rb + c * KPAD + p * RPW + q * 4);
                vv[c] = __hip_atomic_load(src, __ATOMIC_RELAXED,
                                          __HIP_MEMORY_SCOPE_AGENT);
            }
            #pragma unroll
            for (int c = 0; c < NC; ++c) {
                const unsigned long long v = vv[c];
                float4 f;
                f.x = __uint_as_float(((unsigned)( v        & 0xFFFF)) << 16);
                f.y = __uint_as_float(((unsigned)((v >> 16) & 0xFFFF)) << 16);
                f.z = __uint_as_float(((unsigned)((v >> 32) & 0xFFFF)) << 16);
                f.w = __uint_as_float(((unsigned)((v >> 48) & 0xFFFF)) << 16);
                *(float4*)&H[c][p * RPW + q * 4] = f;
            }
        }
        __syncthreads();   // barrier 1: H ready

        // matvec partials: per wave, its 4 rows x 16 cols over its k-half
        #pragma unroll 4
        for (int c = 0; c < NC; ++c) {
            float a0 = 0.f, a1 = 0.f, a2 = 0.f, a3 = 0.f;
            #pragma unroll
            for (int cc = 0; cc < 16; ++cc) {
                const float4 h4 = *(const float4*)&H[c][kbase + cc * 64 + l16 * 4];
                a0 = fmaf(wr[cc].x, h4.x, a0);
                a1 = fmaf(wr[cc].y, h4.y, a1);
                a2 = fmaf(wr[cc].z, h4.z, a2);
                a3 = fmaf(wr[cc].w, h4.w, a3);
            }
            float acc = (a0 + a1) + (a2 + a3);
            acc += __shfl_down(acc, 8, 16);
            acc += __shfl_down(acc, 4, 16);
            acc += __shfl_down(acc, 2, 16);
            acc += __shfl_down(acc, 1, 16);
            if (l16 == 0) partial[kh][c][rloc] = acc;
        }
        __syncthreads();   // barrier 2: partials ready

        // combine k-halves + u_t, tanh, pack bf16 pair, agent-store
        unsigned short* wb = (j & 1) ? bufA : bufB;
        if (tid < NC * RPW / 2) {          // 128 threads, 2 rows each
            const int c = tid >> 3, pr = tid & 7;
            float s0 = partial[0][c][2 * pr]     + partial[1][c][2 * pr];
            float s1 = partial[0][c][2 * pr + 1] + partial[1][c][2 * pr + 1];
            #pragma unroll
            for (int l = 0; l < TT; ++l) {
                const float xl = x_lds[c][l];
                s0 = fmaf(xl, win_lds[2 * pr][l],     s0);
                s1 = fmaf(xl, win_lds[2 * pr + 1][l], s1);
            }
            const float h0 = tanhf(s0), h1 = tanhf(s1);
            hnew[c][2 * pr] = h0; hnew[c][2 * pr + 1] = h1;
            const unsigned pack = (unsigned)f32_to_bf16(h0)
                                | ((unsigned)f32_to_bf16(h1) << 16);
            __hip_atomic_store((unsigned*)(wb + c * KPAD + wg * RPW + 2 * pr),
                               pack, __ATOMIC_RELAXED, __HIP_MEMORY_SCOPE_AGENT);
        }
        __syncthreads();   // barrier 3: stores drained (vmcnt) by their waves

        if (tid == 0)
            __hip_atomic_store(&flags[wg], j + 1, __ATOMIC_RELAXED,
                               __HIP_MEMORY_SCOPE_AGENT);

        // outputs: each col hits h_last at j = 27 (mod 28), j >= 139
        if (j >= WARM + TT - 1 && ((j - (TT - 1)) % TT) == 0 && tid < NC * NO) {
            const int c = tid / NO, o = tid % NO;
            const int m = (CHL / TT) * c + (j - (WARM + TT - 1)) / TT;
            float s = 0.f;
            #pragma unroll
            for (int r = 0; r < RPW; ++r)
                s += hnew[c][r] * wout_lds[o][r];
            atomicAdd(&out[m * NO + o], s);   // off critical path
        }
    }
}

extern "C" void kernel_launch(void* const* d_in, const int* in_sizes, int n_in,
                              void* d_out, int out_size, void* d_ws, size_t ws_size,
                              hipStream_t stream)
{
    const float* x    = (const float*)d_in[0];
    const float* Win  = (const float*)d_in[1];
    const float* Wres = (const float*)d_in[2];
    const float* Wout = (const float*)d_in[3];
    float* out = (float*)d_out;
    unsigned short* ws16 = (unsigned short*)d_ws;

    // zero h buffers (bf16 zeros) + flags; poison must never satisfy protocol
    hipMemsetAsync(d_ws, 0, (size_t)(2 * NC * KPAD) * sizeof(unsigned short)
                              + NWG * sizeof(int), stream);
    hipMemsetAsync(d_out, 0, (size_t)out_size * sizeof(float), stream);

    (void)hipFuncSetAttribute((const void*)esn_chunked2,
                              hipFuncAttributeMaxDynamicSharedMemorySize,
                              NC * KPAD * (int)sizeof(float));

    hipLaunchKernelGGL(esn_chunked2, dim3(NWG), dim3(BLK),
                       NC * KPAD * sizeof(float), stream,
                       x, Win, Wres, Wout, out, ws16);
}